// Round 3
// baseline (2310.710 us; speedup 1.0000x reference)
//
#include <hip/hip_runtime.h>
#include <math.h>

// MultiRNNCell: 2-layer LSTM-imputation scan. B=64, T=128, D=256, H=1024.
// R11 = R10 + incremental dataflow consumption (no more wait-all-64):
//  - consumers poll producer flags in rotated HALF-GROUPS (lanes 0-15 poll 16
//    flags) and load+MFMA each half as it lands; straggler producers are
//    absorbed by the pipeline instead of stalling the whole block at a
//    barrier. Poll's vmcnt drain overlaps in-flight data loads.
//  - imp pull: per-kstep producer groups (8 flags each), polled by lanes 0-31.
//  - signal path: publisher wave drains, lane 0 signals directly (no extra
//    block barrier; cross-step LDS hazards are ordered by the inter-block
//    flag chain fL0->fL1->next-step-polls).
//  - fast transcendentals: sigmoid/tanh via v_exp_f32 + v_rcp_f32 (libm tanhf
//    was ~50+cyc serial on the chain in every epilogue).
// Kept from R10: est-first/register-keep (hides fE), packed one-wave sc0sc1
// publishes, padded reduce strides, XCD rot-stagger, ring buffers + poison
// flags, single dispatch. 256 blocks x 256 thr, ~138 KB LDS -> 1 block/CU.

#define B_ 64
#define T_ 128
#define D_ 256
#define H_ 1024

#define KS0 40          // layer0 frag ksteps: 0-7 imputed (D=256), 8-39 h (H=1024)
#define KS1 32          // layer1 ksteps (H=1024)

#define RS_H   ((size_t)B_ * H_)   // 128 KB per ring slot
#define RS_IMP ((size_t)B_ * D_)   // 32 KB per ring slot

typedef __attribute__((ext_vector_type(8))) short short8;   // 8 bf16
typedef __attribute__((ext_vector_type(4))) float floatx4;  // MFMA C/D
typedef __attribute__((ext_vector_type(4))) unsigned int uint4_;

__device__ __forceinline__ unsigned short f2bf(float x) {
    union { float f; unsigned u; } v; v.f = x;
    unsigned r = v.u + 0x7fffu + ((v.u >> 16) & 1u);  // RNE
    return (unsigned short)(r >> 16);
}
// fast sigmoid/tanh: v_exp_f32 + v_rcp_f32, rel err ~1e-6 << bf16 quantum
__device__ __forceinline__ float sigm_f(float x) {
    return __builtin_amdgcn_rcpf(1.0f + __expf(-x));
}
__device__ __forceinline__ float tanh_f(float x) {
    return 1.0f - 2.0f * __builtin_amdgcn_rcpf(1.0f + __expf(2.0f * x));
}

// write-through stores to the MALL coherence point (bypass L1+L2)
__device__ __forceinline__ void st_u64_sc(void* p, unsigned long long v) {
    asm volatile("global_store_dwordx2 %0, %1, off sc0 sc1"
                 :: "v"(p), "v"(v) : "memory");
}
__device__ __forceinline__ void st_u128_sc(void* p, uint4_ v) {
    asm volatile("global_store_dwordx4 %0, %1, off sc0 sc1"
                 :: "v"(p), "v"(v) : "memory");
}
__device__ __forceinline__ void vm_drain() {
    asm volatile("s_waitcnt vmcnt(0)" ::: "memory");
}
__device__ __forceinline__ void poll1(const int* f) {
    while (__hip_atomic_load(f, __ATOMIC_RELAXED, __HIP_MEMORY_SCOPE_AGENT) != 1) {}
}
__device__ __forceinline__ void set_flag(int* f) {
    __hip_atomic_store(f, 1, __ATOMIC_RELAXED, __HIP_MEMORY_SCOPE_AGENT);
}
__device__ __forceinline__ void wait_ready(const int* flags, int P) {
    if ((int)threadIdx.x < P) poll1(flags + threadIdx.x);
    __syncthreads();
}

#define MFMA __builtin_amdgcn_mfma_f32_16x16x32_bf16

__global__ __launch_bounds__(256, 1) void k_fused(
    const float* __restrict__ Wih0, const float* __restrict__ Whh0,
    const float* __restrict__ bih0, const float* __restrict__ bhh0,
    const float* __restrict__ Wih1, const float* __restrict__ Whh1,
    const float* __restrict__ bih1, const float* __restrict__ bhh1,
    const float* __restrict__ Wout, const float* __restrict__ bout,
    const float* __restrict__ X, const float* __restrict__ Mm,
    unsigned short* __restrict__ hR,    // (T_+1) slots
    unsigned short* __restrict__ h0R,   // T_ slots
    unsigned short* __restrict__ impR,  // T_ slots
    int* __restrict__ fL1, int* __restrict__ fL0, int* __restrict__ fE,
    float* __restrict__ out)
{
    __shared__ unsigned short ldsW[3 * KS0 * 64 * 8];   // 120 KB weight frags
    __shared__ unsigned short ldsWo[32 * 16 * 8];       // 8 KB compact Wout (4 cols)
    __shared__ float redE[2 * 64 * 5];                  // est K-half reduce (pad 5)
    __shared__ float redG[2 * 64 * 13];                 // gate K-half reduce (pad 13)
    __shared__ unsigned short pub[32 * 16];             // 1 KB packed h publish
    __shared__ unsigned short impub[32 * 4];            // 256 B packed imp publish

    const int tid  = threadIdx.x;
    const int lane = tid & 63;
    const int wv   = tid >> 6;
    const int mt   = wv & 1;         // m-tile within the block's 32-row half
    const int kh   = wv >> 1;        // K-half this wave accumulates
    const int r16  = lane & 15, q = lane >> 4;
    const int bx   = blockIdx.x;
    const int rot  = (bx >> 3) & 7;  // XCD-local stagger (bx%8 = XCD id)
    const int rot2 = rot * 2;
    const unsigned short* lfrag = ldsW + lane * 8;   // + fragIdx*512

    if (bx < 128) {
        // =============== combined layer-0 + est blocks ===============
        const int j  = bx & 63;          // gate n-tile (cols 16j..16j+16)
        const int mh = bx >> 6;          // batch half (rows 32mh..32mh+32)
        const int rowA = mh * 32 + mt * 16 + r16;   // A-frag row for this wave
        {   // one-time: Wih0/Whh0 -> bf16 LDS frags (gates i,g,o; dead f removed)
            int n0 = j * 16;
            for (int idx = wv; idx < 3 * KS0; idx += 4) {
                int gi = idx / KS0, k = idx % KS0;
                int grow = (gi == 0) ? 0 : (gi == 1 ? 2 * H_ : 3 * H_);
                int row = grow + n0 + r16;
                const float* src = (k < 8) ? (Wih0 + (size_t)row * D_ + k * 32 + q * 8)
                                           : (Whh0 + (size_t)row * H_ + (k - 8) * 32 + q * 8);
                short8 w;
                #pragma unroll
                for (int e = 0; e < 8; ++e) w[e] = (short)f2bf(src[e]);
                *(short8*)(ldsW + ((size_t)idx * 64 + lane) * 8) = w;
            }
            // compact Wout slice: 4 est cols (dd = 4j..4j+3), slot = kk*16+c*4+q
            for (int s = tid; s < 512; s += 256) {
                int kk = s >> 4, c = (s >> 2) & 3, qq = s & 3;
                const float* src = Wout + (size_t)(4 * j + c) * H_ + kk * 32 + qq * 8;
                short8 w;
                #pragma unroll
                for (int e = 0; e < 8; ++e) w[e] = (short)f2bf(src[e]);
                *(short8*)(ldsWo + (size_t)s * 8) = w;
            }
        }
        __syncthreads();

        const int n = j * 16 + r16;
        const float bi = bih0[n] + bhh0[n];
        const float bg = bih0[2 * H_ + n] + bhh0[2 * H_ + n];
        const float bo = bih0[3 * H_ + n] + bhh0[3 * H_ + n];
        const int dd = 4 * j + (r16 & 3);           // est col (replicated x4)
        const float bout_d = bout[dd];
        const unsigned short* wofrag = ldsWo + ((r16 & 3) * 4 + q) * 8;

        for (int t = 0; t < T_; ++t) {
            float xv[4], mv[4];   // prefetch inputs before polling
            if (kh == 0) {
                #pragma unroll
                for (int r = 0; r < 4; ++r) {
                    int bb = mh * 32 + mt * 16 + q * 4 + r;
                    xv[r] = X [((size_t)bb * T_ + t) * D_ + dd];
                    mv[r] = Mm[((size_t)bb * T_ + t) * D_ + dd];
                }
            }
            asm volatile("" ::: "memory");

            // ---- incremental pull of h(t-1) K-half: two rotated half-groups ----
            const int* flg = fL1 + ((size_t)t * 2 + mh) * 64;
            const unsigned short* aB = hR + (size_t)t * RS_H + (size_t)rowA * H_ + q * 8;
            short8 a[16];
            if (lane < 16) {            // producers of slots 0..7
                int slot = lane >> 1;
                int jj = 2 * (kh * 16 + ((slot + rot2) & 15)) + (lane & 1);
                poll1(flg + jj);
            }
            asm volatile("" ::: "memory");
            #pragma unroll
            for (int k = 0; k < 8; ++k)
                a[k] = *(const short8*)(aB + (kh * 16 + ((k + rot2) & 15)) * 32);
            if (lane < 16) {            // producers of slots 8..15 (drains loads 0-7 concurrently)
                int slot = 8 + (lane >> 1);
                int jj = 2 * (kh * 16 + ((slot + rot2) & 15)) + (lane & 1);
                poll1(flg + jj);
            }
            asm volatile("" ::: "memory");
            #pragma unroll
            for (int k = 8; k < 16; ++k)
                a[k] = *(const short8*)(aB + (kh * 16 + ((k + rot2) & 15)) * 32);

            // ---- est only: 16 MFMAs -> publish imputed ASAP ----
            floatx4 ae = {0.f,0.f,0.f,0.f};
            #pragma unroll
            for (int k = 0; k < 16; ++k) {
                int kk = kh * 16 + ((k + rot2) & 15);
                ae = MFMA(a[k], *(const short8*)(wofrag + kk * 128), ae, 0,0,0);
            }
            if (kh == 1) {
                float* rp = redE + ((size_t)mt * 64 + lane) * 5;
                #pragma unroll
                for (int r = 0; r < 4; ++r) rp[r] = ae[r];
            }
            __syncthreads();
            float estv[4];
            if (kh == 0) {
                const float* rp = redE + ((size_t)mt * 64 + lane) * 5;
                #pragma unroll
                for (int r = 0; r < 4; ++r) estv[r] = ae[r] + rp[r] + bout_d;
                if (r16 < 4) {
                    #pragma unroll
                    for (int r = 0; r < 4; ++r) {
                        float imp = mv[r] * xv[r] + (1.0f - mv[r]) * estv[r];
                        impub[(mt * 16 + q * 4 + r) * 4 + r16] = f2bf(imp);
                    }
                }
            }
            __syncthreads();
            if (wv == 0) {              // packed imp publish: 1 VMEM, then signal
                if (lane < 32) {
                    unsigned long long v = *(const unsigned long long*)(impub + lane * 4);
                    unsigned short* p = impR + (size_t)t * RS_IMP
                                      + (size_t)(mh * 32 + lane) * D_ + 4 * j;
                    st_u64_sc(p, v);
                }
                vm_drain();
                if (lane == 0) set_flag(fE + ((size_t)t * 2 + mh) * 64 + j);
            }

            // ---- hidden phase: gate h-part from registers (no loads) ----
            floatx4 ai = {0.f,0.f,0.f,0.f}, ag = ai, ao = ai;
            #pragma unroll
            for (int k = 0; k < 16; ++k) {
                int kk = kh * 16 + ((k + rot2) & 15);
                ai = MFMA(a[k], *(const short8*)(lfrag + (0 * KS0 + 8 + kk) * 512), ai, 0,0,0);
                ag = MFMA(a[k], *(const short8*)(lfrag + (1 * KS0 + 8 + kk) * 512), ag, 0,0,0);
                ao = MFMA(a[k], *(const short8*)(lfrag + (2 * KS0 + 8 + kk) * 512), ao, 0,0,0);
            }
            // out est write: off the critical chain
            if (kh == 0 && r16 < 4 && t >= 1) {
                #pragma unroll
                for (int r = 0; r < 4; ++r) {
                    int bb = mh * 32 + mt * 16 + q * 4 + r;
                    out[((size_t)bb * T_ + (t - 1)) * D_ + dd] = estv[r];
                }
            }

            // ---- imputed part: per-kstep producer groups (8 flags each) ----
            const int* fe = fE + ((size_t)t * 2 + mh) * 64;
            if (lane < 32) {
                int c = lane >> 3;                       // kstep slot 0..3
                int kkI = kh * 4 + ((c + rot) & 3);
                poll1(fe + 8 * kkI + (lane & 7));
            }
            asm volatile("" ::: "memory");
            {
                const unsigned short* aB2 = impR + (size_t)t * RS_IMP + (size_t)rowA * D_ + q * 8;
                short8 ia[4];
                #pragma unroll
                for (int k = 0; k < 4; ++k) {
                    int kk = kh * 4 + ((k + rot) & 3);
                    ia[k] = *(const short8*)(aB2 + kk * 32);
                }
                #pragma unroll
                for (int k = 0; k < 4; ++k) {
                    int kk = kh * 4 + ((k + rot) & 3);
                    ai = MFMA(ia[k], *(const short8*)(lfrag + (0 * KS0 + kk) * 512), ai, 0,0,0);
                    ag = MFMA(ia[k], *(const short8*)(lfrag + (1 * KS0 + kk) * 512), ag, 0,0,0);
                    ao = MFMA(ia[k], *(const short8*)(lfrag + (2 * KS0 + kk) * 512), ao, 0,0,0);
                }
            }
            // gate K-half reduce -> h0 epilogue -> packed publish
            if (kh == 1) {
                float* rp = redG + ((size_t)mt * 64 + lane) * 13;
                #pragma unroll
                for (int r = 0; r < 4; ++r) { rp[r] = ai[r]; rp[4 + r] = ag[r]; rp[8 + r] = ao[r]; }
            }
            __syncthreads();
            if (kh == 0) {
                const float* rp = redG + ((size_t)mt * 64 + lane) * 13;
                #pragma unroll
                for (int r = 0; r < 4; ++r) {
                    float c = sigm_f(ai[r] + rp[r] + bi) * tanh_f(ag[r] + rp[4 + r] + bg);
                    float h = sigm_f(ao[r] + rp[8 + r] + bo) * tanh_f(c);
                    pub[(mt * 16 + q * 4 + r) * 16 + r16] = f2bf(h);
                }
            }
            __syncthreads();
            if (wv == 0) {              // packed h0 publish: 1 VMEM, then signal
                uint4_ v = *(const uint4_*)(pub + lane * 8);
                unsigned short* p = h0R + (size_t)t * RS_H
                                  + (size_t)(mh * 32 + (lane >> 1)) * H_ + j * 16 + (lane & 1) * 8;
                st_u128_sc(p, v);
                vm_drain();
                if (lane == 0) set_flag(fL0 + ((size_t)t * 2 + mh) * 64 + j);
            }
        }
        // final projection: est from h(T-1) (slot T_) -> out[:, T-1, :]
        wait_ready(fL1 + ((size_t)T_ * 2 + mh) * 64, 64);
        short8 a[16];
        const unsigned short* aB = hR + (size_t)T_ * RS_H + (size_t)rowA * H_ + q * 8;
        #pragma unroll
        for (int k = 0; k < 16; ++k) {
            int kk = kh * 16 + ((k + rot2) & 15);
            a[k] = *(const short8*)(aB + kk * 32);
        }
        floatx4 ae = {0.f,0.f,0.f,0.f};
        #pragma unroll
        for (int k = 0; k < 16; ++k) {
            int kk = kh * 16 + ((k + rot2) & 15);
            ae = MFMA(a[k], *(const short8*)(wofrag + kk * 128), ae, 0,0,0);
        }
        if (kh == 1) {
            float* rp = redE + ((size_t)mt * 64 + lane) * 5;
            #pragma unroll
            for (int r = 0; r < 4; ++r) rp[r] = ae[r];
        }
        __syncthreads();
        if (kh == 0 && r16 < 4) {
            const float* rp = redE + ((size_t)mt * 64 + lane) * 5;
            #pragma unroll
            for (int r = 0; r < 4; ++r) {
                int bb = mh * 32 + mt * 16 + q * 4 + r;
                out[((size_t)bb * T_ + (T_ - 1)) * D_ + dd] = ae[r] + rp[r] + bout_d;
            }
        }
    } else {
        // =============== layer-1 blocks ===============
        const int i  = bx - 128;
        const int j1 = i & 63;           // n-tile
        const int mh = i >> 6;           // batch half
        const int rowA = mh * 32 + mt * 16 + r16;
        {   // one-time: folded W1 = Wih1+Whh1 -> bf16 LDS frags
            int n0 = j1 * 16;
            for (int idx = wv; idx < 3 * KS1; idx += 4) {
                int gi = idx / KS1, k = idx % KS1;
                int grow = (gi == 0) ? 0 : (gi == 1 ? 2 * H_ : 3 * H_);
                size_t o = (size_t)(grow + n0 + r16) * H_ + k * 32 + q * 8;
                short8 w;
                #pragma unroll
                for (int e = 0; e < 8; ++e) w[e] = (short)f2bf(Wih1[o + e] + Whh1[o + e]);
                *(short8*)(ldsW + ((size_t)idx * 64 + lane) * 8) = w;
            }
        }
        __syncthreads();
        const int n = j1 * 16 + r16;
        const float bi = bih1[n] + bhh1[n];
        const float bg = bih1[2 * H_ + n] + bhh1[2 * H_ + n];
        const float bo = bih1[3 * H_ + n] + bhh1[3 * H_ + n];
        // h(-1) = 0 -> packed zeros into hR slot 0, then flag it
        if (wv == 0) {
            uint4_ z = {0u, 0u, 0u, 0u};
            unsigned short* p = hR + (size_t)(mh * 32 + (lane >> 1)) * H_ + j1 * 16 + (lane & 1) * 8;
            st_u128_sc(p, z);
            vm_drain();
            if (lane == 0) set_flag(fL1 + (size_t)mh * 64 + j1);
        }
        for (int t = 0; t < T_; ++t) {
            // ---- incremental pull of h0(t) K-half: two rotated half-groups ----
            const int* flg = fL0 + ((size_t)t * 2 + mh) * 64;
            const unsigned short* aB = h0R + (size_t)t * RS_H + (size_t)rowA * H_ + q * 8;
            short8 a[16];
            if (lane < 16) {
                int slot = lane >> 1;
                int jj = 2 * (kh * 16 + ((slot + rot2) & 15)) + (lane & 1);
                poll1(flg + jj);
            }
            asm volatile("" ::: "memory");
            #pragma unroll
            for (int k = 0; k < 8; ++k)
                a[k] = *(const short8*)(aB + (kh * 16 + ((k + rot2) & 15)) * 32);
            if (lane < 16) {
                int slot = 8 + (lane >> 1);
                int jj = 2 * (kh * 16 + ((slot + rot2) & 15)) + (lane & 1);
                poll1(flg + jj);
            }
            asm volatile("" ::: "memory");
            #pragma unroll
            for (int k = 8; k < 16; ++k)
                a[k] = *(const short8*)(aB + (kh * 16 + ((k + rot2) & 15)) * 32);

            floatx4 li = {0.f,0.f,0.f,0.f}, lg = li, lo = li;
            #pragma unroll
            for (int k = 0; k < 8; ++k) {
                int kk = kh * 16 + ((k + rot2) & 15);
                li = MFMA(a[k], *(const short8*)(lfrag + (0 * KS1 + kk) * 512), li, 0,0,0);
                lg = MFMA(a[k], *(const short8*)(lfrag + (1 * KS1 + kk) * 512), lg, 0,0,0);
                lo = MFMA(a[k], *(const short8*)(lfrag + (2 * KS1 + kk) * 512), lo, 0,0,0);
            }
            #pragma unroll
            for (int k = 8; k < 16; ++k) {
                int kk = kh * 16 + ((k + rot2) & 15);
                li = MFMA(a[k], *(const short8*)(lfrag + (0 * KS1 + kk) * 512), li, 0,0,0);
                lg = MFMA(a[k], *(const short8*)(lfrag + (1 * KS1 + kk) * 512), lg, 0,0,0);
                lo = MFMA(a[k], *(const short8*)(lfrag + (2 * KS1 + kk) * 512), lo, 0,0,0);
            }
            if (kh == 1) {
                float* rp = redG + ((size_t)mt * 64 + lane) * 13;
                #pragma unroll
                for (int r = 0; r < 4; ++r) { rp[r] = li[r]; rp[4 + r] = lg[r]; rp[8 + r] = lo[r]; }
            }
            __syncthreads();
            float hv[4];
            if (kh == 0) {
                const float* rp = redG + ((size_t)mt * 64 + lane) * 13;
                #pragma unroll
                for (int r = 0; r < 4; ++r) {
                    float c = sigm_f(li[r] + rp[r] + bi) * tanh_f(lg[r] + rp[4 + r] + bg);
                    hv[r] = sigm_f(lo[r] + rp[8 + r] + bo) * tanh_f(c);
                    pub[(mt * 16 + q * 4 + r) * 16 + r16] = f2bf(hv[r]);
                }
            }
            __syncthreads();
            if (wv == 0) {              // packed h publish: 1 VMEM, then signal
                uint4_ v = *(const uint4_*)(pub + lane * 8);
                unsigned short* p = hR + (size_t)(t + 1) * RS_H
                                  + (size_t)(mh * 32 + (lane >> 1)) * H_ + j1 * 16 + (lane & 1) * 8;
                st_u128_sc(p, v);
                vm_drain();
                if (lane == 0) set_flag(fL1 + ((size_t)(t + 1) * 2 + mh) * 64 + j1);
            }
            if (t == T_ - 1 && kh == 0) {   // h_final, off the chain
                #pragma unroll
                for (int r = 0; r < 4; ++r) {
                    int bb = mh * 32 + mt * 16 + q * 4 + r;
                    out[(size_t)B_ * T_ * D_ + (size_t)bb * H_ + n] = hv[r];
                }
            }
        }
    }
}

extern "C" void kernel_launch(void* const* d_in, const int* in_sizes, int n_in,
                              void* d_out, int out_size, void* d_ws, size_t ws_size,
                              hipStream_t stream) {
    const float* X    = (const float*)d_in[0];
    const float* Mm   = (const float*)d_in[1];
    const float* Wih0 = (const float*)d_in[2];
    const float* Whh0 = (const float*)d_in[3];
    const float* bih0 = (const float*)d_in[4];
    const float* bhh0 = (const float*)d_in[5];
    const float* Wih1 = (const float*)d_in[6];
    const float* Whh1 = (const float*)d_in[7];
    const float* bih1 = (const float*)d_in[8];
    const float* bhh1 = (const float*)d_in[9];
    const float* Wout = (const float*)d_in[10];
    const float* bout = (const float*)d_in[11];
    float* out = (float*)d_out;

    // ring workspace (256B aligned); no init: flags compare ==1 vs 0xAA
    // poison, hR slot 0 zeroed in-kernel by l1 blocks.
    char* ws = (char*)d_ws;
    size_t off = 0;
    auto alloc = [&](size_t bytes) { char* p = ws + off; off = (off + bytes + 255) & ~(size_t)255; return p; };
    unsigned short* hR   = (unsigned short*)alloc((size_t)(T_ + 1) * RS_H * 2);
    unsigned short* h0R  = (unsigned short*)alloc((size_t)T_ * RS_H * 2);
    unsigned short* impR = (unsigned short*)alloc((size_t)T_ * RS_IMP * 2);
    int*            fL1  = (int*)alloc((size_t)(T_ + 1) * 128 * 4);   // [t][mh][64]
    int*            fL0  = (int*)alloc((size_t)T_ * 128 * 4);         // [t][mh][64]
    int*            fE   = (int*)alloc((size_t)T_ * 128 * 4);         // [t][mh][64]

    k_fused<<<256, 256, 0, stream>>>(Wih0, Whh0, bih0, bhh0, Wih1, Whh1, bih1, bhh1,
                                     Wout, bout, X, Mm,
                                     hR, h0R, impR, fL1, fL0, fE, out);
}

// Round 4
// 1834.813 us; speedup vs baseline: 1.2594x; 1.2594x over previous
//
#include <hip/hip_runtime.h>
#include <math.h>

// MultiRNNCell: 2-layer LSTM-imputation scan. B=64, T=128, D=256, H=1024.
// R12 = R10 (best, 2125us) + mh->XCD-half placement + 16-way rot stagger
//       + fast transcendentals. (R11's incremental polling REVERTED: atomic
//       poll spins drain vmcnt(0), serializing in-flight data loads.)
//  - placement: mh = (bx>>2)&1, j = (bx&3)|((bx>>3)<<2)  => XCDs 0-3 host
//    only mh=0 blocks, XCDs 4-7 only mh=1 (bx%8 = XCD id). Each XCD's 16
//    same-role blocks pull the SAME 64KB half-slot: per-XCD unique EA line
//    fills for the h/h0 exchanges HALVE, sibling L2 dedup goes 8->16-way.
//  - rot16 = (bx>>3)&15: 16 siblings first-touch disjoint 16ths of the pull.
//  - sigmoid/tanh via v_exp_f32 + v_rcp_f32 (epilogue dep chains on the
//    critical path; rel err ~1e-6 << bf16 quantum).
// Kept from R10: est-first/register-keep (hides fE hop), packed one-wave
// sc0sc1 publishes, padded reduce strides, ring buffers + poison flags,
// single dispatch. 256 blocks x 256 thr, ~138 KB LDS -> 1 block/CU.

#define B_ 64
#define T_ 128
#define D_ 256
#define H_ 1024

#define KS0 40          // layer0 frag ksteps: 0-7 imputed (D=256), 8-39 h (H=1024)
#define KS1 32          // layer1 ksteps (H=1024)

#define RS_H   ((size_t)B_ * H_)   // 128 KB per ring slot
#define RS_IMP ((size_t)B_ * D_)   // 32 KB per ring slot

typedef __attribute__((ext_vector_type(8))) short short8;   // 8 bf16
typedef __attribute__((ext_vector_type(4))) float floatx4;  // MFMA C/D
typedef __attribute__((ext_vector_type(4))) unsigned int uint4_;

__device__ __forceinline__ unsigned short f2bf(float x) {
    union { float f; unsigned u; } v; v.f = x;
    unsigned r = v.u + 0x7fffu + ((v.u >> 16) & 1u);  // RNE
    return (unsigned short)(r >> 16);
}
// fast sigmoid/tanh: v_exp_f32 + v_rcp_f32
__device__ __forceinline__ float sigm_f(float x) {
    return __builtin_amdgcn_rcpf(1.0f + __expf(-x));
}
__device__ __forceinline__ float tanh_f(float x) {
    return 1.0f - 2.0f * __builtin_amdgcn_rcpf(1.0f + __expf(2.0f * x));
}

// write-through stores to the MALL coherence point (bypass L1+L2)
__device__ __forceinline__ void st_u64_sc(void* p, unsigned long long v) {
    asm volatile("global_store_dwordx2 %0, %1, off sc0 sc1"
                 :: "v"(p), "v"(v) : "memory");
}
__device__ __forceinline__ void st_u128_sc(void* p, uint4_ v) {
    asm volatile("global_store_dwordx4 %0, %1, off sc0 sc1"
                 :: "v"(p), "v"(v) : "memory");
}
__device__ __forceinline__ void vm_drain() {
    asm volatile("s_waitcnt vmcnt(0)" ::: "memory");
}

__device__ __forceinline__ void wait_ready(const int* flags, int P) {
    if ((int)threadIdx.x < P) {
        while (__hip_atomic_load(flags + threadIdx.x, __ATOMIC_RELAXED,
                                 __HIP_MEMORY_SCOPE_AGENT) != 1) {}
    }
    __syncthreads();
}
__device__ __forceinline__ void signal_flag(int* flag) {
    __syncthreads();    // storing wave's vm_drain precedes this barrier
    if (threadIdx.x == 0)
        __hip_atomic_store(flag, 1, __ATOMIC_RELAXED, __HIP_MEMORY_SCOPE_AGENT);
}

#define MFMA __builtin_amdgcn_mfma_f32_16x16x32_bf16

__global__ __launch_bounds__(256, 1) void k_fused(
    const float* __restrict__ Wih0, const float* __restrict__ Whh0,
    const float* __restrict__ bih0, const float* __restrict__ bhh0,
    const float* __restrict__ Wih1, const float* __restrict__ Whh1,
    const float* __restrict__ bih1, const float* __restrict__ bhh1,
    const float* __restrict__ Wout, const float* __restrict__ bout,
    const float* __restrict__ X, const float* __restrict__ Mm,
    unsigned short* __restrict__ hR,    // (T_+1) slots
    unsigned short* __restrict__ h0R,   // T_ slots
    unsigned short* __restrict__ impR,  // T_ slots
    int* __restrict__ fL1, int* __restrict__ fL0, int* __restrict__ fE,
    float* __restrict__ out)
{
    __shared__ unsigned short ldsW[3 * KS0 * 64 * 8];   // 120 KB weight frags
    __shared__ unsigned short ldsWo[32 * 16 * 8];       // 8 KB compact Wout (4 cols)
    __shared__ float redE[2 * 64 * 5];                  // est K-half reduce (pad 5)
    __shared__ float redG[2 * 64 * 13];                 // gate K-half reduce (pad 13)
    __shared__ unsigned short pub[32 * 16];             // 1 KB packed h publish
    __shared__ unsigned short impub[32 * 4];            // 256 B packed imp publish

    const int tid  = threadIdx.x;
    const int lane = tid & 63;
    const int wv   = tid >> 6;
    const int mt   = wv & 1;         // m-tile within the block's 32-row half
    const int kh   = wv >> 1;        // K-half this wave accumulates
    const int r16  = lane & 15, q = lane >> 4;
    const int bx   = blockIdx.x;
    // mh->XCD-half placement + 16-way sibling rotation (bx%8 = XCD id):
    //   XCD 0-3 host mh=0, XCD 4-7 host mh=1; 16 same-(role,mh) blocks per
    //   XCD share one half-slot pull, each first-touching a disjoint 16th.
    const int rot16 = (bx >> 3) & 15;
    const int rotI  = rot16 & 3;     // imp-part rotation (4 ksteps/wave)
    const unsigned short* lfrag = ldsW + lane * 8;   // + fragIdx*512

    if (bx < 128) {
        // =============== combined layer-0 + est blocks ===============
        const int j  = (bx & 3) | ((bx >> 3) << 2);   // gate n-tile (16 cols)
        const int mh = (bx >> 2) & 1;                 // batch half = XCD half
        const int rowA = mh * 32 + mt * 16 + r16;     // A-frag row for this wave
        {   // one-time: Wih0/Whh0 -> bf16 LDS frags (gates i,g,o; dead f removed)
            int n0 = j * 16;
            for (int idx = wv; idx < 3 * KS0; idx += 4) {
                int gi = idx / KS0, k = idx % KS0;
                int grow = (gi == 0) ? 0 : (gi == 1 ? 2 * H_ : 3 * H_);
                int row = grow + n0 + r16;
                const float* src = (k < 8) ? (Wih0 + (size_t)row * D_ + k * 32 + q * 8)
                                           : (Whh0 + (size_t)row * H_ + (k - 8) * 32 + q * 8);
                short8 w;
                #pragma unroll
                for (int e = 0; e < 8; ++e) w[e] = (short)f2bf(src[e]);
                *(short8*)(ldsW + ((size_t)idx * 64 + lane) * 8) = w;
            }
            // compact Wout slice: 4 est cols (dd = 4j..4j+3), slot = kk*16+c*4+q
            for (int s = tid; s < 512; s += 256) {
                int kk = s >> 4, c = (s >> 2) & 3, qq = s & 3;
                const float* src = Wout + (size_t)(4 * j + c) * H_ + kk * 32 + qq * 8;
                short8 w;
                #pragma unroll
                for (int e = 0; e < 8; ++e) w[e] = (short)f2bf(src[e]);
                *(short8*)(ldsWo + (size_t)s * 8) = w;
            }
        }
        __syncthreads();

        const int n = j * 16 + r16;
        const float bi = bih0[n] + bhh0[n];
        const float bg = bih0[2 * H_ + n] + bhh0[2 * H_ + n];
        const float bo = bih0[3 * H_ + n] + bhh0[3 * H_ + n];
        const int dd = 4 * j + (r16 & 3);           // est col (replicated x4)
        const float bout_d = bout[dd];
        const unsigned short* wofrag = ldsWo + ((r16 & 3) * 4 + q) * 8;

        for (int t = 0; t < T_; ++t) {
            float xv[4], mv[4];   // prefetch inputs before waiting
            if (kh == 0) {
                #pragma unroll
                for (int r = 0; r < 4; ++r) {
                    int bb = mh * 32 + mt * 16 + q * 4 + r;
                    xv[r] = X [((size_t)bb * T_ + t) * D_ + dd];
                    mv[r] = Mm[((size_t)bb * T_ + t) * D_ + dd];
                }
            }
            asm volatile("" ::: "memory");
            wait_ready(fL1 + ((size_t)t * 2 + mh) * 64, 64);   // h(t-1) half ready

            // ---- pull h(t-1) K-half into registers (issue all loads first) ----
            short8 a[16];
            const unsigned short* aB = hR + (size_t)t * RS_H + (size_t)rowA * H_ + q * 8;
            #pragma unroll
            for (int k = 0; k < 16; ++k) {
                int kk = kh * 16 + ((k + rot16) & 15);
                a[k] = *(const short8*)(aB + kk * 32);
            }
            // ---- est only: 16 MFMAs -> publish imputed ASAP ----
            floatx4 ae = {0.f,0.f,0.f,0.f};
            #pragma unroll
            for (int k = 0; k < 16; ++k) {
                int kk = kh * 16 + ((k + rot16) & 15);
                ae = MFMA(a[k], *(const short8*)(wofrag + kk * 128), ae, 0,0,0);
            }
            if (kh == 1) {
                float* rp = redE + ((size_t)mt * 64 + lane) * 5;
                #pragma unroll
                for (int r = 0; r < 4; ++r) rp[r] = ae[r];
            }
            __syncthreads();
            float estv[4];
            if (kh == 0) {
                const float* rp = redE + ((size_t)mt * 64 + lane) * 5;
                #pragma unroll
                for (int r = 0; r < 4; ++r) estv[r] = ae[r] + rp[r] + bout_d;
                if (r16 < 4) {
                    #pragma unroll
                    for (int r = 0; r < 4; ++r) {
                        float imp = mv[r] * xv[r] + (1.0f - mv[r]) * estv[r];
                        impub[(mt * 16 + q * 4 + r) * 4 + r16] = f2bf(imp);
                    }
                }
            }
            __syncthreads();
            if (wv == 0) {              // packed imp publish: 1 VMEM (32 x 8B)
                if (lane < 32) {
                    unsigned long long v = *(const unsigned long long*)(impub + lane * 4);
                    unsigned short* p = impR + (size_t)t * RS_IMP
                                      + (size_t)(mh * 32 + lane) * D_ + 4 * j;
                    st_u64_sc(p, v);
                }
                vm_drain();
            }
            signal_flag(fE + ((size_t)t * 2 + mh) * 64 + j);

            // ---- hidden phase: gate h-part from registers (no loads) ----
            floatx4 ai = {0.f,0.f,0.f,0.f}, ag = ai, ao = ai;
            #pragma unroll
            for (int k = 0; k < 16; ++k) {
                int kk = kh * 16 + ((k + rot16) & 15);
                ai = MFMA(a[k], *(const short8*)(lfrag + (0 * KS0 + 8 + kk) * 512), ai, 0,0,0);
                ag = MFMA(a[k], *(const short8*)(lfrag + (1 * KS0 + 8 + kk) * 512), ag, 0,0,0);
                ao = MFMA(a[k], *(const short8*)(lfrag + (2 * KS0 + 8 + kk) * 512), ao, 0,0,0);
            }
            // out est write: off the critical chain
            if (kh == 0 && r16 < 4 && t >= 1) {
                #pragma unroll
                for (int r = 0; r < 4; ++r) {
                    int bb = mh * 32 + mt * 16 + q * 4 + r;
                    out[((size_t)bb * T_ + (t - 1)) * D_ + dd] = estv[r];
                }
            }
            wait_ready(fE + ((size_t)t * 2 + mh) * 64, 64);    // likely already set
            {   // imputed part (this wave: 4 of 8 ksteps)
                const unsigned short* aB2 = impR + (size_t)t * RS_IMP + (size_t)rowA * D_ + q * 8;
                short8 ia[4];
                #pragma unroll
                for (int k = 0; k < 4; ++k) {
                    int kk = kh * 4 + ((k + rotI) & 3);
                    ia[k] = *(const short8*)(aB2 + kk * 32);
                }
                #pragma unroll
                for (int k = 0; k < 4; ++k) {
                    int kk = kh * 4 + ((k + rotI) & 3);
                    ai = MFMA(ia[k], *(const short8*)(lfrag + (0 * KS0 + kk) * 512), ai, 0,0,0);
                    ag = MFMA(ia[k], *(const short8*)(lfrag + (1 * KS0 + kk) * 512), ag, 0,0,0);
                    ao = MFMA(ia[k], *(const short8*)(lfrag + (2 * KS0 + kk) * 512), ao, 0,0,0);
                }
            }
            // gate K-half reduce -> h0 epilogue -> packed publish
            if (kh == 1) {
                float* rp = redG + ((size_t)mt * 64 + lane) * 13;
                #pragma unroll
                for (int r = 0; r < 4; ++r) { rp[r] = ai[r]; rp[4 + r] = ag[r]; rp[8 + r] = ao[r]; }
            }
            __syncthreads();
            if (kh == 0) {
                const float* rp = redG + ((size_t)mt * 64 + lane) * 13;
                #pragma unroll
                for (int r = 0; r < 4; ++r) {
                    float c = sigm_f(ai[r] + rp[r] + bi) * tanh_f(ag[r] + rp[4 + r] + bg);
                    float h = sigm_f(ao[r] + rp[8 + r] + bo) * tanh_f(c);
                    pub[(mt * 16 + q * 4 + r) * 16 + r16] = f2bf(h);
                }
            }
            __syncthreads();
            if (wv == 0) {              // packed h0 publish: 1 VMEM (64 x 16B)
                uint4_ v = *(const uint4_*)(pub + lane * 8);
                unsigned short* p = h0R + (size_t)t * RS_H
                                  + (size_t)(mh * 32 + (lane >> 1)) * H_ + j * 16 + (lane & 1) * 8;
                st_u128_sc(p, v);
                vm_drain();
            }
            signal_flag(fL0 + ((size_t)t * 2 + mh) * 64 + j);
        }
        // final projection: est from h(T-1) (slot T_) -> out[:, T-1, :]
        wait_ready(fL1 + ((size_t)T_ * 2 + mh) * 64, 64);
        short8 a[16];
        const unsigned short* aB = hR + (size_t)T_ * RS_H + (size_t)rowA * H_ + q * 8;
        #pragma unroll
        for (int k = 0; k < 16; ++k) {
            int kk = kh * 16 + ((k + rot16) & 15);
            a[k] = *(const short8*)(aB + kk * 32);
        }
        floatx4 ae = {0.f,0.f,0.f,0.f};
        #pragma unroll
        for (int k = 0; k < 16; ++k) {
            int kk = kh * 16 + ((k + rot16) & 15);
            ae = MFMA(a[k], *(const short8*)(wofrag + kk * 128), ae, 0,0,0);
        }
        if (kh == 1) {
            float* rp = redE + ((size_t)mt * 64 + lane) * 5;
            #pragma unroll
            for (int r = 0; r < 4; ++r) rp[r] = ae[r];
        }
        __syncthreads();
        if (kh == 0 && r16 < 4) {
            const float* rp = redE + ((size_t)mt * 64 + lane) * 5;
            #pragma unroll
            for (int r = 0; r < 4; ++r) {
                int bb = mh * 32 + mt * 16 + q * 4 + r;
                out[((size_t)bb * T_ + (T_ - 1)) * D_ + dd] = ae[r] + rp[r] + bout_d;
            }
        }
    } else {
        // =============== layer-1 blocks ===============
        const int i  = bx - 128;                       // (bx%8 = i%8 = XCD id)
        const int j1 = (i & 3) | ((i >> 3) << 2);      // n-tile
        const int mh = (i >> 2) & 1;                   // batch half = XCD half
        const int rowA = mh * 32 + mt * 16 + r16;
        {   // one-time: folded W1 = Wih1+Whh1 -> bf16 LDS frags
            int n0 = j1 * 16;
            for (int idx = wv; idx < 3 * KS1; idx += 4) {
                int gi = idx / KS1, k = idx % KS1;
                int grow = (gi == 0) ? 0 : (gi == 1 ? 2 * H_ : 3 * H_);
                size_t o = (size_t)(grow + n0 + r16) * H_ + k * 32 + q * 8;
                short8 w;
                #pragma unroll
                for (int e = 0; e < 8; ++e) w[e] = (short)f2bf(Wih1[o + e] + Whh1[o + e]);
                *(short8*)(ldsW + ((size_t)idx * 64 + lane) * 8) = w;
            }
        }
        __syncthreads();
        const int n = j1 * 16 + r16;
        const float bi = bih1[n] + bhh1[n];
        const float bg = bih1[2 * H_ + n] + bhh1[2 * H_ + n];
        const float bo = bih1[3 * H_ + n] + bhh1[3 * H_ + n];
        // h(-1) = 0 -> packed zeros into hR slot 0, then flag it
        if (wv == 0) {
            uint4_ z = {0u, 0u, 0u, 0u};
            unsigned short* p = hR + (size_t)(mh * 32 + (lane >> 1)) * H_ + j1 * 16 + (lane & 1) * 8;
            st_u128_sc(p, z);
            vm_drain();
        }
        signal_flag(fL1 + (size_t)mh * 64 + j1);
        for (int t = 0; t < T_; ++t) {
            wait_ready(fL0 + ((size_t)t * 2 + mh) * 64, 64);   // h0(t) half ready
            short8 a[16];
            const unsigned short* aB = h0R + (size_t)t * RS_H + (size_t)rowA * H_ + q * 8;
            #pragma unroll
            for (int k = 0; k < 16; ++k) {
                int kk = kh * 16 + ((k + rot16) & 15);
                a[k] = *(const short8*)(aB + kk * 32);
            }
            floatx4 li = {0.f,0.f,0.f,0.f}, lg = li, lo = li;
            #pragma unroll
            for (int k = 0; k < 16; ++k) {
                int kk = kh * 16 + ((k + rot16) & 15);
                li = MFMA(a[k], *(const short8*)(lfrag + (0 * KS1 + kk) * 512), li, 0,0,0);
                lg = MFMA(a[k], *(const short8*)(lfrag + (1 * KS1 + kk) * 512), lg, 0,0,0);
                lo = MFMA(a[k], *(const short8*)(lfrag + (2 * KS1 + kk) * 512), lo, 0,0,0);
            }
            if (kh == 1) {
                float* rp = redG + ((size_t)mt * 64 + lane) * 13;
                #pragma unroll
                for (int r = 0; r < 4; ++r) { rp[r] = li[r]; rp[4 + r] = lg[r]; rp[8 + r] = lo[r]; }
            }
            __syncthreads();
            float hv[4];
            if (kh == 0) {
                const float* rp = redG + ((size_t)mt * 64 + lane) * 13;
                #pragma unroll
                for (int r = 0; r < 4; ++r) {
                    float c = sigm_f(li[r] + rp[r] + bi) * tanh_f(lg[r] + rp[4 + r] + bg);
                    hv[r] = sigm_f(lo[r] + rp[8 + r] + bo) * tanh_f(c);
                    pub[(mt * 16 + q * 4 + r) * 16 + r16] = f2bf(hv[r]);
                }
            }
            __syncthreads();
            if (wv == 0) {              // packed h publish: 1 VMEM (64 x 16B)
                uint4_ v = *(const uint4_*)(pub + lane * 8);
                unsigned short* p = hR + (size_t)(t + 1) * RS_H
                                  + (size_t)(mh * 32 + (lane >> 1)) * H_ + j1 * 16 + (lane & 1) * 8;
                st_u128_sc(p, v);
                vm_drain();
            }
            signal_flag(fL1 + ((size_t)(t + 1) * 2 + mh) * 64 + j1);
            if (t == T_ - 1 && kh == 0) {   // h_final, off the chain
                #pragma unroll
                for (int r = 0; r < 4; ++r) {
                    int bb = mh * 32 + mt * 16 + q * 4 + r;
                    out[(size_t)B_ * T_ * D_ + (size_t)bb * H_ + n] = hv[r];
                }
            }
        }
    }
}

extern "C" void kernel_launch(void* const* d_in, const int* in_sizes, int n_in,
                              void* d_out, int out_size, void* d_ws, size_t ws_size,
                              hipStream_t stream) {
    const float* X    = (const float*)d_in[0];
    const float* Mm   = (const float*)d_in[1];
    const float* Wih0 = (const float*)d_in[2];
    const float* Whh0 = (const float*)d_in[3];
    const float* bih0 = (const float*)d_in[4];
    const float* bhh0 = (const float*)d_in[5];
    const float* Wih1 = (const float*)d_in[6];
    const float* Whh1 = (const float*)d_in[7];
    const float* bih1 = (const float*)d_in[8];
    const float* bhh1 = (const float*)d_in[9];
    const float* Wout = (const float*)d_in[10];
    const float* bout = (const float*)d_in[11];
    float* out = (float*)d_out;

    // ring workspace (256B aligned); no init: flags compare ==1 vs 0xAA
    // poison, hR slot 0 zeroed in-kernel by l1 blocks.
    char* ws = (char*)d_ws;
    size_t off = 0;
    auto alloc = [&](size_t bytes) { char* p = ws + off; off = (off + bytes + 255) & ~(size_t)255; return p; };
    unsigned short* hR   = (unsigned short*)alloc((size_t)(T_ + 1) * RS_H * 2);
    unsigned short* h0R  = (unsigned short*)alloc((size_t)T_ * RS_H * 2);
    unsigned short* impR = (unsigned short*)alloc((size_t)T_ * RS_IMP * 2);
    int*            fL1  = (int*)alloc((size_t)(T_ + 1) * 128 * 4);   // [t][mh][64]
    int*            fL0  = (int*)alloc((size_t)T_ * 128 * 4);         // [t][mh][64]
    int*            fE   = (int*)alloc((size_t)T_ * 128 * 4);         // [t][mh][64]

    k_fused<<<256, 256, 0, stream>>>(Wih0, Whh0, bih0, bhh0, Wih1, Whh1, bih1, bhh1,
                                     Wout, bout, X, Mm,
                                     hR, h0R, impR, fL1, fL0, fE, out);
}